// Round 13
// baseline (629.867 us; speedup 1.0000x reference)
//
#include <hip/hip_runtime.h>
#include <hip/hip_bf16.h>

#define N_NODES 100000
#define N_EDGES 300000
#define CH 256
#define EPS 1e-5f
#define AGG_BLOCKS 3125   // N_NODES / 32 exactly
#define Y_TILES 782       // ceil(N_NODES/128)
#define Y_TILES_PAD 784   // padded to multiple of 8

typedef __hip_bfloat16 bf16;
typedef __attribute__((ext_vector_type(8))) short bf16x8_t;  // 8 bf16 (4 VGPRs)
typedef __attribute__((ext_vector_type(4))) float f32x4_t;   // 4 fp32 acc

__device__ __forceinline__ unsigned short f2bf(float f) {
    bf16 h = __float2bfloat16(f);
    return __builtin_bit_cast(unsigned short, h);
}
__device__ __forceinline__ float bf2f(unsigned short u) {
    unsigned int x = ((unsigned int)u) << 16;  // exact widening
    return __builtin_bit_cast(float, x);
}
__device__ __forceinline__ float bflo(unsigned int w) {
    return __builtin_bit_cast(float, w << 16);
}
__device__ __forceinline__ float bfhi(unsigned int w) {
    return __builtin_bit_cast(float, w & 0xffff0000u);
}
__device__ __forceinline__ unsigned pack2(float a, float b) {
    return (unsigned)f2bf(a) | ((unsigned)f2bf(b) << 16);
}
__device__ __forceinline__ void store_val(bf16* p, float v) { *p = __float2bfloat16(v); }

__device__ __forceinline__ void async_copy16(const void* g, void* l) {
    __builtin_amdgcn_global_load_lds((const __attribute__((address_space(1))) void*)g,
                                     (__attribute__((address_space(3))) void*)l, 16, 0, 0);
}

// ================= CSR build =================
__global__ void k_zero_int(int* __restrict__ p, int n) {
    int i = blockIdx.x * 256 + threadIdx.x;
    if (i < n) p[i] = 0;
}
__global__ void k_count_deg(const int* __restrict__ dst, int* __restrict__ deg) {
    int e = blockIdx.x * 256 + threadIdx.x;
    if (e < N_EDGES) atomicAdd(&deg[dst[e]], 1);
}
// per-256-chunk sums of deg; also computes dinv (fused, both read deg)
__global__ void k_block_sums(const int* __restrict__ deg, int* __restrict__ bsum,
                             float* __restrict__ dinv) {
    __shared__ int s[256];
    int t = threadIdx.x;
    int i = blockIdx.x * 256 + t;
    int dg = (i < N_NODES) ? deg[i] : 0;
    if (i < N_NODES) dinv[i] = rsqrtf((float)(dg + 1));  // +1 self loop
    s[t] = dg;
    __syncthreads();
    for (int off = 128; off > 0; off >>= 1) {
        if (t < off) s[t] += s[t + off];
        __syncthreads();
    }
    if (t == 0) bsum[blockIdx.x] = s[0];
}
__global__ void k_scan_bsums(int* __restrict__ bsum, int nb) {
    __shared__ int s[512];
    int t = threadIdx.x;
    int v = (t < nb) ? bsum[t] : 0;
    s[t] = v;
    __syncthreads();
    for (int off = 1; off < 512; off <<= 1) {
        int u = (t >= off) ? s[t - off] : 0;
        __syncthreads();
        s[t] += u;
        __syncthreads();
    }
    if (t < nb) bsum[t] = s[t] - v;  // exclusive
}
__global__ void k_row_ptr(const int* __restrict__ deg, const int* __restrict__ bsum,
                          int* __restrict__ row_ptr) {
    __shared__ int s[256];
    int t = threadIdx.x;
    int i = blockIdx.x * 256 + t;
    int v = (i < N_NODES) ? deg[i] : 0;
    s[t] = v;
    __syncthreads();
    for (int off = 1; off < 256; off <<= 1) {
        int u = (t >= off) ? s[t - off] : 0;
        __syncthreads();
        s[t] += u;
        __syncthreads();
    }
    if (i < N_NODES) row_ptr[i] = bsum[blockIdx.x] + s[t] - v;  // exclusive
    if (blockIdx.x == 0 && t == 0) row_ptr[N_NODES] = N_EDGES;
}
// scatter: also records wedge = dinv[d]*dinv[s], dst2 (dst per CSR entry), eid (orig edge id)
__global__ void k_scatter(const int* __restrict__ src, const int* __restrict__ dst,
                          const int* __restrict__ row_ptr, int* __restrict__ cursor,
                          const float* __restrict__ dinv,
                          int* __restrict__ col, float* __restrict__ wedge,
                          int* __restrict__ dst2, int* __restrict__ eid) {
    int e = blockIdx.x * 256 + threadIdx.x;
    if (e < N_EDGES) {
        int d = dst[e], s = src[e];
        int p = atomicAdd(&cursor[d], 1);
        int idx = row_ptr[d] + p;
        col[idx] = s;
        wedge[idx] = dinv[d] * dinv[s];
        dst2[idx] = d;
        eid[idx] = e;
    }
}

// ================= all weight transposes in one kernel =================
__global__ void k_transpose_all(const float* __restrict__ W1, const float* __restrict__ W2,
                                const float* __restrict__ W3, const float* __restrict__ fc1w,
                                bf16* __restrict__ wt) {
    int which = blockIdx.x >> 8;  // 0..4
    int idx = ((blockIdx.x & 255) << 8) + threadIdx.x;
    int n = idx >> 8, k = idx & 255;
    const float* W; int ro = 0;
    switch (which) {
        case 0: W = W1; break;
        case 1: W = W2; break;
        case 2: W = W3; break;
        case 3: W = fc1w; break;
        default: W = fc1w; ro = 256; break;
    }
    wt[(size_t)which * 65536 + (size_t)n * 256 + k] =
        __float2bfloat16(W[(size_t)(ro + k) * 256 + n]);
}

// ================= casts =================
__global__ void k_cast_bf16_v4(const float* __restrict__ x, unsigned short* __restrict__ y) {
    int i = blockIdx.x * 256 + threadIdx.x;  // over NF/4
    float4 v = ((const float4*)x)[i];
    ushort4 o;
    o.x = f2bf(v.x); o.y = f2bf(v.y); o.z = f2bf(v.z); o.w = f2bf(v.w);
    ((ushort4*)y)[i] = o;
}
// in-place BN apply + relu on bf16 buffer
__global__ void k_bn_relu_bf16(unsigned short* __restrict__ x, const float* __restrict__ scale,
                               const float* __restrict__ shift) {
    int i = blockIdx.x * 256 + threadIdx.x;  // over NF/4
    ushort4 m = ((ushort4*)x)[i];
    int c = (i & 63) * 4;
    float4 sc = *(const float4*)(scale + c);
    float4 sh = *(const float4*)(shift + c);
    ushort4 o;
    o.x = f2bf(fmaxf(bf2f(m.x) * sc.x + sh.x, 0.f));
    o.y = f2bf(fmaxf(bf2f(m.y) * sc.y + sh.y, 0.f));
    o.z = f2bf(fmaxf(bf2f(m.z) * sc.z + sh.z, 0.f));
    o.w = f2bf(fmaxf(bf2f(m.w) * sc.w + sh.w, 0.f));
    ((ushort4*)x)[i] = o;
}

// ====== bf16 MFMA GEMM (async staged, XCD-swizzled tiles) ======
// C[M x (NX*128)] = A @ Bt^T (+bias on cols<256). 128x128 tile, BK=64, 4 waves.
// 1-D grid; tiles sharing a row-tile land on the same XCD (indices ≡ mod 8).
template <int NX, bool BIAS>
__global__ __launch_bounds__(256) void k_gemm_mfma(const bf16* __restrict__ A,
                                                   const bf16* __restrict__ Bt,
                                                   bf16* __restrict__ C, int M, int ldc,
                                                   const float* __restrict__ bias256) {
    constexpr int LOG2NX = (NX == 4) ? 2 : 1;
    int id = blockIdx.x;
    int rg = (id & 7) + 8 * (id >> (3 + LOG2NX));
    int ct = (id >> 3) & (NX - 1);
    if (rg >= Y_TILES) return;
    const int row0 = rg * 128;
    const int col0 = ct * 128;

    __shared__ bf16 As[128 * 64];
    __shared__ bf16 Bs[128 * 64];
    const int tid = threadIdx.x;
    const int lane = tid & 63;
    const int w = tid >> 6;
    const int wr = w >> 1, wc = w & 1;
    const int lr = lane & 15, quad = lane >> 4;

    f32x4_t acc[4][4] = {};

    for (int k0 = 0; k0 < 256; k0 += 64) {
#pragma unroll
        for (int i = 0; i < 4; ++i) {
            int j = i * 256 + tid;
            int r = j >> 3, c = j & 7;
            int gk = ((c ^ (r & 7)) << 3);
            int gr = row0 + r; gr = gr < M ? gr : M - 1;
            async_copy16(A + (size_t)gr * 256 + k0 + gk, (void*)(As + j * 8));
            async_copy16(Bt + (size_t)(col0 + r) * 256 + k0 + gk, (void*)(Bs + j * 8));
        }
        __syncthreads();
#pragma unroll
        for (int ks = 0; ks < 2; ++ks) {
            bf16x8_t af[4], bfr[4];
#pragma unroll
            for (int mi = 0; mi < 4; ++mi) {
                int m = wr * 64 + mi * 16 + lr;
                int c = (ks * 4 + quad) ^ (m & 7);
                af[mi] = *(const bf16x8_t*)(As + m * 64 + c * 8);
            }
#pragma unroll
            for (int ni = 0; ni < 4; ++ni) {
                int n = wc * 64 + ni * 16 + lr;
                int c = (ks * 4 + quad) ^ (n & 7);
                bfr[ni] = *(const bf16x8_t*)(Bs + n * 64 + c * 8);
            }
#pragma unroll
            for (int mi = 0; mi < 4; ++mi)
#pragma unroll
                for (int ni = 0; ni < 4; ++ni)
                    acc[mi][ni] = __builtin_amdgcn_mfma_f32_16x16x32_bf16(
                        af[mi], bfr[ni], acc[mi][ni], 0, 0, 0);
        }
        __syncthreads();
    }
    float bv[4];
#pragma unroll
    for (int ni = 0; ni < 4; ++ni) {
        int colg = col0 + wc * 64 + ni * 16 + lr;
        bv[ni] = (BIAS && colg < 256) ? bias256[colg] : 0.f;
    }
#pragma unroll
    for (int mi = 0; mi < 4; ++mi) {
#pragma unroll
        for (int r = 0; r < 4; ++r) {
            int row = row0 + wr * 64 + mi * 16 + quad * 4 + r;
            if (row < M) {
#pragma unroll
                for (int ni = 0; ni < 4; ++ni) {
                    int colg = col0 + wc * 64 + ni * 16 + lr;
                    store_val(C + (size_t)row * ldc + colg, acc[mi][ni][r] + bv[ni]);
                }
            }
        }
    }
}

// ===== CSR aggregation: 32 lanes/node (uint4=8ch per lane), 32 nodes/block =====
// STATS: part[blockIdx][c] = sum over block's 32 nodes (c<256: sum; c>=256: sumsq).
template <bool STATS>
__global__ __launch_bounds__(256) void k_agg_csr(const unsigned short* __restrict__ xw,
                                                 const int* __restrict__ row_ptr,
                                                 const int* __restrict__ col,
                                                 const float* __restrict__ wedge,
                                                 const float* __restrict__ dinv,
                                                 const float* __restrict__ bias,
                                                 bf16* __restrict__ out,
                                                 float* __restrict__ part) {
    __shared__ float sred[8][256];
    __shared__ float qred[8][256];
    int g = threadIdx.x >> 5, lh = threadIdx.x & 31;  // 8 half-waves x 32 lanes
    int base = blockIdx.x * 32 + g * 4;               // exact: AGG_BLOCKS*32 == N_NODES
    const uint4* xwv = (const uint4*)xw;              // bf16 row = 32 uint4
    float4 b0 = ((const float4*)bias)[lh * 2];
    float4 b1 = ((const float4*)bias)[lh * 2 + 1];
    float s8[8] = {}, q8[8] = {};
#pragma unroll
    for (int n = 0; n < 4; ++n) {
        int node = base + n;
        int beg = row_ptr[node], end = row_ptr[node + 1];
        float dv = dinv[node];
        uint4 xr = xwv[(size_t)node * 32 + lh];
        float s2 = dv * dv;
        float a0 = s2 * bflo(xr.x), a1 = s2 * bfhi(xr.x);
        float a2 = s2 * bflo(xr.y), a3 = s2 * bfhi(xr.y);
        float a4 = s2 * bflo(xr.z), a5 = s2 * bfhi(xr.z);
        float a6 = s2 * bflo(xr.w), a7 = s2 * bfhi(xr.w);
        int i = beg;
        for (; i + 2 <= end; i += 2) {  // 2 outstanding gathers per chain
            int sa = col[i], sb = col[i + 1];
            float wa = wedge[i], wb = wedge[i + 1];
            uint4 ma = xwv[(size_t)sa * 32 + lh];
            uint4 mb = xwv[(size_t)sb * 32 + lh];
            a0 += wa * bflo(ma.x) + wb * bflo(mb.x);
            a1 += wa * bfhi(ma.x) + wb * bfhi(mb.x);
            a2 += wa * bflo(ma.y) + wb * bflo(mb.y);
            a3 += wa * bfhi(ma.y) + wb * bfhi(mb.y);
            a4 += wa * bflo(ma.z) + wb * bflo(mb.z);
            a5 += wa * bfhi(ma.z) + wb * bfhi(mb.z);
            a6 += wa * bflo(ma.w) + wb * bflo(mb.w);
            a7 += wa * bfhi(ma.w) + wb * bfhi(mb.w);
        }
        if (i < end) {
            int sa = col[i];
            float wa = wedge[i];
            uint4 ma = xwv[(size_t)sa * 32 + lh];
            a0 += wa * bflo(ma.x); a1 += wa * bfhi(ma.x);
            a2 += wa * bflo(ma.y); a3 += wa * bfhi(ma.y);
            a4 += wa * bflo(ma.z); a5 += wa * bfhi(ma.z);
            a6 += wa * bflo(ma.w); a7 += wa * bfhi(ma.w);
        }
        a0 += b0.x; a1 += b0.y; a2 += b0.z; a3 += b0.w;
        a4 += b1.x; a5 += b1.y; a6 += b1.z; a7 += b1.w;
        uint4 o;
        o.x = pack2(a0, a1); o.y = pack2(a2, a3);
        o.z = pack2(a4, a5); o.w = pack2(a6, a7);
        ((uint4*)(out + (size_t)node * CH))[lh] = o;
        if (STATS) {
            s8[0] += a0; s8[1] += a1; s8[2] += a2; s8[3] += a3;
            s8[4] += a4; s8[5] += a5; s8[6] += a6; s8[7] += a7;
            q8[0] += a0 * a0; q8[1] += a1 * a1; q8[2] += a2 * a2; q8[3] += a3 * a3;
            q8[4] += a4 * a4; q8[5] += a5 * a5; q8[6] += a6 * a6; q8[7] += a7 * a7;
        }
    }
    if (STATS) {
#pragma unroll
        for (int j = 0; j < 8; ++j) {
            sred[g][lh * 8 + j] = s8[j];
            qred[g][lh * 8 + j] = q8[j];
        }
        __syncthreads();
        int t = threadIdx.x;  // channel 0..255
        float ss = 0.f, qq = 0.f;
#pragma unroll
        for (int gg = 0; gg < 8; ++gg) {
            ss += sred[gg][t];
            qq += qred[gg][t];
        }
        part[(size_t)blockIdx.x * 512 + t] = ss;
        part[(size_t)blockIdx.x * 512 + 256 + t] = qq;
    }
}

// one wave per channel: lanes stride over AGG_BLOCKS partials, shuffle-reduce
__global__ __launch_bounds__(256) void k_bn_finalize(const float* __restrict__ part,
                                                     const float* __restrict__ g,
                                                     const float* __restrict__ be,
                                                     float* __restrict__ scale,
                                                     float* __restrict__ shift) {
    int wave = threadIdx.x >> 6, lane = threadIdx.x & 63;
    int c = blockIdx.x * 4 + wave;  // 0..255
    float s = 0.f, q = 0.f;
    for (int j = lane; j < AGG_BLOCKS; j += 64) {
        s += part[(size_t)j * 512 + c];
        q += part[(size_t)j * 512 + 256 + c];
    }
#pragma unroll
    for (int off = 32; off > 0; off >>= 1) {
        s += __shfl_down(s, off, 64);
        q += __shfl_down(q, off, 64);
    }
    if (lane == 0) {
        float mu = s * (1.0f / N_NODES);
        float var = q * (1.0f / N_NODES) - mu * mu;
        float sc = g[c] * rsqrtf(var + EPS);
        scale[c] = sc;
        shift[c] = be[c] - mu * sc;
    }
}

// ======= edge scoring over dst-sorted CSR entries (v[dst] gets L2 locality) =======
// 4 entries/wave, 16 lanes each, 16 ch/lane; fc1_b pre-added to u columns.
__global__ __launch_bounds__(256) void k_edge_score(
        const unsigned short* __restrict__ uv,
        const int* __restrict__ col, const int* __restrict__ dst2,
        const int* __restrict__ eid, const int* __restrict__ neg,
        const float* __restrict__ fc2_w, const float* __restrict__ fc2_b,
        float* __restrict__ out) {
    int wave = threadIdx.x >> 6, lane = threadIdx.x & 63;
    int qtr = lane >> 4, l = lane & 15;
    int i = blockIdx.x * 16 + wave * 4 + qtr;
    if (i >= N_EDGES) return;
    int s = col[i], d = dst2[i], e = eid[i];
    int g = neg[e];
    const uint4* uvv = (const uint4*)uv;  // row = 64 uint4 (u: 0..31, v: 32..63)
    uint4 u0 = uvv[(size_t)s * 64 + l * 2];
    uint4 u1 = uvv[(size_t)s * 64 + l * 2 + 1];
    uint4 p0 = uvv[(size_t)d * 64 + 32 + l * 2];
    uint4 p1 = uvv[(size_t)d * 64 + 32 + l * 2 + 1];
    uint4 n0 = uvv[(size_t)g * 64 + 32 + l * 2];
    uint4 n1 = uvv[(size_t)g * 64 + 32 + l * 2 + 1];
    float4 w0 = ((const float4*)fc2_w)[l * 4];
    float4 w1 = ((const float4*)fc2_w)[l * 4 + 1];
    float4 w2 = ((const float4*)fc2_w)[l * 4 + 2];
    float4 w3 = ((const float4*)fc2_w)[l * 4 + 3];

    float t0 = bflo(u0.x), t1 = bfhi(u0.x), t2 = bflo(u0.y), t3 = bfhi(u0.y);
    float t4 = bflo(u0.z), t5 = bfhi(u0.z), t6 = bflo(u0.w), t7 = bfhi(u0.w);
    float t8 = bflo(u1.x), t9 = bfhi(u1.x), ta = bflo(u1.y), tb = bfhi(u1.y);
    float tc = bflo(u1.z), td = bfhi(u1.z), te = bflo(u1.w), tf = bfhi(u1.w);

    float accp =
        fmaxf(t0 + bflo(p0.x), 0.f) * w0.x + fmaxf(t1 + bfhi(p0.x), 0.f) * w0.y +
        fmaxf(t2 + bflo(p0.y), 0.f) * w0.z + fmaxf(t3 + bfhi(p0.y), 0.f) * w0.w +
        fmaxf(t4 + bflo(p0.z), 0.f) * w1.x + fmaxf(t5 + bfhi(p0.z), 0.f) * w1.y +
        fmaxf(t6 + bflo(p0.w), 0.f) * w1.z + fmaxf(t7 + bfhi(p0.w), 0.f) * w1.w +
        fmaxf(t8 + bflo(p1.x), 0.f) * w2.x + fmaxf(t9 + bfhi(p1.x), 0.f) * w2.y +
        fmaxf(ta + bflo(p1.y), 0.f) * w2.z + fmaxf(tb + bfhi(p1.y), 0.f) * w2.w +
        fmaxf(tc + bflo(p1.z), 0.f) * w3.x + fmaxf(td + bfhi(p1.z), 0.f) * w3.y +
        fmaxf(te + bflo(p1.w), 0.f) * w3.z + fmaxf(tf + bfhi(p1.w), 0.f) * w3.w;
    float accn =
        fmaxf(t0 + bflo(n0.x), 0.f) * w0.x + fmaxf(t1 + bfhi(n0.x), 0.f) * w0.y +
        fmaxf(t2 + bflo(n0.y), 0.f) * w0.z + fmaxf(t3 + bfhi(n0.y), 0.f) * w0.w +
        fmaxf(t4 + bflo(n0.z), 0.f) * w1.x + fmaxf(t5 + bfhi(n0.z), 0.f) * w1.y +
        fmaxf(t6 + bflo(n0.w), 0.f) * w1.z + fmaxf(t7 + bfhi(n0.w), 0.f) * w1.w +
        fmaxf(t8 + bflo(n1.x), 0.f) * w2.x + fmaxf(t9 + bfhi(n1.x), 0.f) * w2.y +
        fmaxf(ta + bflo(n1.y), 0.f) * w2.z + fmaxf(tb + bfhi(n1.y), 0.f) * w2.w +
        fmaxf(tc + bflo(n1.z), 0.f) * w3.x + fmaxf(td + bfhi(n1.z), 0.f) * w3.y +
        fmaxf(te + bflo(n1.w), 0.f) * w3.z + fmaxf(tf + bfhi(n1.w), 0.f) * w3.w;
#pragma unroll
    for (int off = 8; off > 0; off >>= 1) {
        accp += __shfl_down(accp, off, 64);
        accn += __shfl_down(accn, off, 64);
    }
    if (l == 0) {
        float bb = fc2_b[0];
        out[e] = 1.0f / (1.0f + expf(-(accp + bb)));
        out[N_EDGES + e] = 1.0f / (1.0f + expf(-(accn + bb)));
    }
}

extern "C" void kernel_launch(void* const* d_in, const int* in_sizes, int n_in,
                              void* d_out, int out_size, void* d_ws, size_t ws_size,
                              hipStream_t stream) {
    const float* node_feat = (const float*)d_in[0];
    const int* src = (const int*)d_in[1];
    const int* dst = (const int*)d_in[2];
    const int* neg = (const int*)d_in[3];
    const float* W1 = (const float*)d_in[4];  const float* b1 = (const float*)d_in[5];
    const float* W2 = (const float*)d_in[6];  const float* b2 = (const float*)d_in[7];
    const float* W3 = (const float*)d_in[8];  const float* b3 = (const float*)d_in[9];
    const float* g1 = (const float*)d_in[10]; const float* be1 = (const float*)d_in[11];
    const float* g2 = (const float*)d_in[12]; const float* be2 = (const float*)d_in[13];
    const float* fc1_w = (const float*)d_in[14]; const float* fc1_b = (const float*)d_in[15];
    const float* fc2_w = (const float*)d_in[16]; const float* fc2_b = (const float*)d_in[17];
    float* out = (float*)d_out;

    // ---- workspace layout (~218 MB total) ----
    const size_t NF = (size_t)N_NODES * CH;  // 25,600,000
    bf16* UV = (bf16*)d_ws;                  // [node][512] u|v (2*NF)
    bf16* Xbf = UV + 2 * NF;                 // bf16 activations / agg out / z (NF)
    bf16* XwBf = Xbf + NF;                   // bf16 GEMM output xw (NF)
    bf16* wt = XwBf + NF;                    // 5 * 65536 (wt1,wt2,wt3,wtu,wtv)
    float* dinv = (float*)(wt + 5 * 65536);
    float* bnpart = dinv + N_NODES;          // AGG_BLOCKS * 512 (6.4 MB)
    float* scale = bnpart + (size_t)AGG_BLOCKS * 512;
    float* shift = scale + CH;
    float* wedge = shift + CH;               // E floats
    int* ideg = (int*)(wedge + N_EDGES);     // N (cursor follows: zeroed together)
    int* cursor = ideg + N_NODES;
    int* row_ptr = cursor + N_NODES;
    int* col = row_ptr + N_NODES + 1;        // E
    int* dst2 = col + N_EDGES;               // E
    int* eid = dst2 + N_EDGES;               // E
    int* bsum = eid + N_EDGES;               // 512
    (void)ws_size;

    int gemmBlocks = 2 * Y_TILES_PAD;          // 1568 (N=256, NX=2)
    int uvBlocks = 4 * Y_TILES_PAD;            // 3136 (N=512, NX=4)
    int nodeBlocks = (N_NODES + 255) / 256;    // 391
    int edgeBlocks = (N_EDGES + 255) / 256;
    int v4Blocks = (int)(NF / 4 / 256);        // 25000
    int scoreBlocks = (N_EDGES + 15) / 16;     // 18750

    // ---- CSR build + dinv + edge weights ----
    k_zero_int<<<(2 * N_NODES + 255) / 256, 256, 0, stream>>>(ideg, 2 * N_NODES);
    k_count_deg<<<edgeBlocks, 256, 0, stream>>>(dst, ideg);
    k_block_sums<<<nodeBlocks, 256, 0, stream>>>(ideg, bsum, dinv);
    k_scan_bsums<<<1, 512, 0, stream>>>(bsum, nodeBlocks);
    k_row_ptr<<<nodeBlocks, 256, 0, stream>>>(ideg, bsum, row_ptr);
    k_scatter<<<edgeBlocks, 256, 0, stream>>>(src, dst, row_ptr, cursor, dinv,
                                              col, wedge, dst2, eid);

    // ---- all weight transposes ----
    k_transpose_all<<<1280, 256, 0, stream>>>(W1, W2, W3, fc1_w, wt);

    // ---- layer 1 ----
    k_cast_bf16_v4<<<v4Blocks, 256, 0, stream>>>(node_feat, (unsigned short*)Xbf);
    k_gemm_mfma<2, false><<<gemmBlocks, 256, 0, stream>>>(Xbf, wt, XwBf, N_NODES, 256, nullptr);
    k_agg_csr<true><<<AGG_BLOCKS, 256, 0, stream>>>((unsigned short*)XwBf, row_ptr, col,
                                                    wedge, dinv, b1, Xbf, bnpart);
    k_bn_finalize<<<64, 256, 0, stream>>>(bnpart, g1, be1, scale, shift);
    k_bn_relu_bf16<<<v4Blocks, 256, 0, stream>>>((unsigned short*)Xbf, scale, shift);

    // ---- layer 2 ----
    k_gemm_mfma<2, false><<<gemmBlocks, 256, 0, stream>>>(Xbf, wt + 65536, XwBf, N_NODES, 256, nullptr);
    k_agg_csr<true><<<AGG_BLOCKS, 256, 0, stream>>>((unsigned short*)XwBf, row_ptr, col,
                                                    wedge, dinv, b2, Xbf, bnpart);
    k_bn_finalize<<<64, 256, 0, stream>>>(bnpart, g2, be2, scale, shift);
    k_bn_relu_bf16<<<v4Blocks, 256, 0, stream>>>((unsigned short*)Xbf, scale, shift);

    // ---- layer 3: agg writes z (bf16) into Xbf ----
    k_gemm_mfma<2, false><<<gemmBlocks, 256, 0, stream>>>(Xbf, wt + 2 * 65536, XwBf, N_NODES, 256, nullptr);
    k_agg_csr<false><<<AGG_BLOCKS, 256, 0, stream>>>((unsigned short*)XwBf, row_ptr, col,
                                                     wedge, dinv, b3, Xbf, nullptr);

    // ---- link predictor: UV = z @ [wtu|wtv]^T + [fc1_b|0] ----
    k_gemm_mfma<4, true><<<uvBlocks, 256, 0, stream>>>(Xbf, wt + 3 * 65536, UV, N_NODES, 512, fc1_b);
    k_edge_score<<<scoreBlocks, 256, 0, stream>>>((unsigned short*)UV, col, dst2, eid, neg,
                                                  fc2_w, fc2_b, out);
}